// Round 1
// baseline (492.267 us; speedup 1.0000x reference)
//
#include <hip/hip_runtime.h>
#include <hip/hip_bf16.h>
#include <stdint.h>

#define N_ROWS 131072
#define D_IN   512
#define D_OUT  512
#define BM     64
#define BK     64
#define NKT    (D_IN / BK)   // 8
#define THREADS 512

typedef short s8v __attribute__((ext_vector_type(8)));   // 8 bf16 bits (4 VGPRs)
typedef float f4v __attribute__((ext_vector_type(4)));   // MFMA acc
typedef unsigned int u32;

// fp32 -> bf16 bits, round-to-nearest-even
__device__ __forceinline__ unsigned short f2bf(float f) {
    u32 b = __builtin_bit_cast(u32, f);
    b += 0x7FFFu + ((b >> 16) & 1u);
    return (unsigned short)(b >> 16);
}

// ---------------------------------------------------------------------------
// W fp32 [k][n] -> bf16 ws, transposed + tiled + XOR-swizzled:
//   ws[((kt*512 + n)*8 + g')*8 + j] = bf16(W[(kt*64 + (g'^(n&7))*8 + j)*512 + n])
// so that a linear 64KB global_load_lds per k-tile gives a swizzled LDS layout
// whose b128 fragment reads are ~conflict-free.
// ---------------------------------------------------------------------------
__global__ void convert_w(const float* __restrict__ W, unsigned short* __restrict__ wsb) {
    int t = blockIdx.x * blockDim.x + threadIdx.x;   // 0 .. 262143
    int j  = t & 7;
    int gp = (t >> 3) & 7;
    int n  = (t >> 6) & 511;
    int kt = t >> 15;
    int k = kt * 64 + ((gp ^ (n & 7)) << 3) + j;
    wsb[t] = f2bf(W[k * 512 + n]);
}

// ---------------------------------------------------------------------------
// Fused GEMM: x (fp32, binary) @ W(bf16, pre-swizzled in ws) + bias
// BM=64 rows/block, BN=512 (full D_OUT -> x read exactly once), BK=64.
// 512 threads = 8 waves; wave w owns cols [w*64, w*64+64), 4x4 frags of
// 16x16x32 bf16 MFMA. Double-buffered LDS, pipelined staging.
// ---------------------------------------------------------------------------
__global__ __launch_bounds__(THREADS, 2) void sparse_dense_gemm(
    const float* __restrict__ X, const unsigned short* __restrict__ Wb,
    const float* __restrict__ bias, float* __restrict__ Y)
{
    extern __shared__ char smem[];
    unsigned short* bufB = (unsigned short*)smem;               // [2][512*64] bf16 = 2*64KB
    unsigned short* bufA = (unsigned short*)(smem + 131072);    // [2][64*72]  bf16 = 2*9KB

    const int tid  = threadIdx.x;
    const int lane = tid & 63;
    const int wv   = tid >> 6;          // 0..7
    const int r0   = blockIdx.x * BM;

    // A staging mapping: thread -> (row, k-group), global reads coalesced
    const int arow = tid >> 3;          // 0..63
    const int akg  = tid & 7;           // 0..7
    const float* xsrc = X + (size_t)(r0 + arow) * D_IN + akg * 8;

    f4v acc[4][4];
    #pragma unroll
    for (int mf = 0; mf < 4; ++mf)
        #pragma unroll
        for (int nf = 0; nf < 4; ++nf)
            acc[mf][nf] = f4v{0.f, 0.f, 0.f, 0.f};

    const int c = lane & 15;            // frag col / row-group selector
    const int q = lane >> 4;            // quad 0..3

    // ---- helpers ----
    auto stageB = [&](int kt, int buf) {
        const unsigned short* src = Wb + kt * 32768;
        unsigned short* dst = bufB + buf * 32768;
        #pragma unroll
        for (int r = 0; r < 8; ++r) {
            int o = (r * 512 + tid) * 8;   // element offset; *2 bytes -> lane*16B pattern
            __builtin_amdgcn_global_load_lds(
                (const __attribute__((address_space(1))) u32*)(src + o),
                (__attribute__((address_space(3)))       u32*)(dst + o),
                16, 0, 0);
        }
    };
    auto writeA = [&](float4 a0, float4 a1, int buf) {
        u32 w0 = (u32)f2bf(a0.x) | ((u32)f2bf(a0.y) << 16);
        u32 w1 = (u32)f2bf(a0.z) | ((u32)f2bf(a0.w) << 16);
        u32 w2 = (u32)f2bf(a1.x) | ((u32)f2bf(a1.y) << 16);
        u32 w3 = (u32)f2bf(a1.z) | ((u32)f2bf(a1.w) << 16);
        uint4 pk = make_uint4(w0, w1, w2, w3);
        *(uint4*)(bufA + buf * (64 * 72) + arow * 72 + akg * 8) = pk;  // 144B rows: 16B aligned
    };

    // ---- prologue: stage kt=0 into buffer 0 ----
    float4 pa0 = *(const float4*)(xsrc);
    float4 pa1 = *(const float4*)(xsrc + 4);
    stageB(0, 0);
    writeA(pa0, pa1, 0);

    int p = 0;
    for (int kt = 0; kt < NKT; ++kt) {
        __syncthreads();   // staging of buffer p complete; buffer p^1 free
        const int np = p ^ 1;
        if (kt + 1 < NKT) {
            // issue next-iter loads NOW so they fly during the MFMA phase
            pa0 = *(const float4*)(xsrc + (kt + 1) * BK);
            pa1 = *(const float4*)(xsrc + (kt + 1) * BK + 4);
            stageB(kt + 1, np);
        }

        // ---- compute on buffer p ----
        const unsigned short* Ab = bufA + p * (64 * 72);
        const unsigned short* Bb = bufB + p * 32768;
        #pragma unroll
        for (int ks = 0; ks < 2; ++ks) {
            s8v af[4], bfr[4];
            #pragma unroll
            for (int mf = 0; mf < 4; ++mf)
                af[mf] = *(const s8v*)(Ab + (mf * 16 + c) * 72 + ks * 32 + q * 8);
            #pragma unroll
            for (int nf = 0; nf < 4; ++nf) {
                int n  = wv * 64 + nf * 16 + c;
                int gp = (ks * 4 + q) ^ (n & 7);
                bfr[nf] = *(const s8v*)(Bb + n * 64 + gp * 8);
            }
            #pragma unroll
            for (int mf = 0; mf < 4; ++mf)
                #pragma unroll
                for (int nf = 0; nf < 4; ++nf)
                    acc[mf][nf] = __builtin_amdgcn_mfma_f32_16x16x32_bf16(
                        af[mf], bfr[nf], acc[mf][nf], 0, 0, 0);
        }

        if (kt + 1 < NKT) writeA(pa0, pa1, np);
        p = np;
    }

    // ---- epilogue: C/D layout col=lane&15, row=(lane>>4)*4+i ----
    #pragma unroll
    for (int nf = 0; nf < 4; ++nf) {
        int col = wv * 64 + nf * 16 + c;
        float bv = bias[col];
        #pragma unroll
        for (int mf = 0; mf < 4; ++mf) {
            #pragma unroll
            for (int i = 0; i < 4; ++i) {
                int row = r0 + mf * 16 + q * 4 + i;
                Y[(size_t)row * D_OUT + col] = acc[mf][nf][i] + bv;
            }
        }
    }
}

extern "C" void kernel_launch(void* const* d_in, const int* in_sizes, int n_in,
                              void* d_out, int out_size, void* d_ws, size_t ws_size,
                              hipStream_t stream) {
    const float* X    = (const float*)d_in[0];
    const float* W    = (const float*)d_in[1];
    const float* bias = (const float*)d_in[2];
    float* Y          = (float*)d_out;
    unsigned short* wsb = (unsigned short*)d_ws;   // 512 KB bf16 W copy

    // allow >64KB dynamic LDS (gfx950 supports 160KB/workgroup)
    static_assert(2 * 512 * 64 * 2 + 2 * 64 * 72 * 2 == 149504, "lds layout");
    (void)hipFuncSetAttribute((const void*)sparse_dense_gemm,
                              hipFuncAttributeMaxDynamicSharedMemorySize, 149504);

    convert_w<<<1024, 256, 0, stream>>>(W, wsb);
    sparse_dense_gemm<<<N_ROWS / BM, THREADS, 149504, stream>>>(X, wsb, bias, Y);
}